// Round 6
// baseline (170.065 us; speedup 1.0000x reference)
//
#include <hip/hip_runtime.h>
#include <hip/hip_bf16.h>

#define LNUM 13
#define FDIM 768
#define SDIM 512
#define BNUM 32
#define H1DIM 512
#define H2DIM 256
#define GA 2048            // kA blocks; work-stealing makes grid size non-critical
#define MAXCH 4096         // max chunks: 32 * ceil(511/4)

// ---------------- Kernel A: work-stealing chunk partials (chunk = (b, 4 s-positions))
// Each WAVE pops a chunk id from a global counter and computes sum/sumsq of the
// layer-weighted word vectors for its 4 s-positions, writing partial slot [c].
// Slot c's value is independent of which wave processes it -> deterministic.
__global__ __launch_bounds__(192) void kA_partials(
    const float* __restrict__ x, const int* __restrict__ lengths,
    const float* __restrict__ lw, float* __restrict__ partial,
    unsigned int* __restrict__ counter) {
  __shared__ int lenS[BNUM];
  __shared__ int cumS[BNUM + 1];
  __shared__ float wS[LNUM];
  const int tid = threadIdx.x;
  const int lane = tid & 63;

  if (tid < BNUM) lenS[tid] = lengths[tid];
  __syncthreads();
  if (tid == 0) {
    int acc = 0; cumS[0] = 0;
    #pragma unroll
    for (int b = 0; b < BNUM; ++b) { acc += (lenS[b] + 3) >> 2; cumS[b + 1] = acc; }
    float m = lw[0];
    #pragma unroll
    for (int l = 1; l < LNUM; ++l) m = fmaxf(m, lw[l]);
    float e[LNUM]; float s = 0.f;
    #pragma unroll
    for (int l = 0; l < LNUM; ++l) { e[l] = expf(lw[l] - m); s += e[l]; }
    #pragma unroll
    for (int l = 0; l < LNUM; ++l) wS[l] = e[l] / s;
  }
  __syncthreads();
  const int T4 = cumS[BNUM];

  float w[LNUM];
  #pragma unroll
  for (int l = 0; l < LNUM; ++l) w[l] = wS[l];

  for (;;) {
    unsigned int c = 0;
    if (lane == 0) c = atomicAdd(counter, 1u);
    c = __shfl((int)c, 0, 64);
    if ((int)c >= T4) break;

    // binary search: largest b with cumS[b] <= c
    int lo = 0, hi = BNUM;
    while (hi - lo > 1) { int mid = (lo + hi) >> 1; if ((int)c >= cumS[mid]) lo = mid; else hi = mid; }
    const int b  = lo;
    const int s0 = ((int)c - cumS[b]) << 2;
    const int s1 = min(s0 + 4, lenS[b]);

    float4 sum0 = make_float4(0.f,0.f,0.f,0.f), sum1 = sum0, sum2 = sum0;
    float4 sq0 = sum0, sq1 = sum0, sq2 = sum0;
    // lane covers floats [lane*4, lane*4+4) of each 256-float segment; 3 segments = 768
    const float* xb = x + (size_t)b * SDIM * (LNUM * FDIM) + (size_t)lane * 4;

    for (int s = s0; s < s1; ++s) {
      const float* xs = xb + (size_t)s * (LNUM * FDIM);
      float4 w0 = make_float4(0.f,0.f,0.f,0.f), w1 = w0, w2 = w0;
      #pragma unroll
      for (int l = 0; l < LNUM; ++l) {
        const float wl = w[l];
        float4 v0 = *reinterpret_cast<const float4*>(xs + l * FDIM);
        float4 v1 = *reinterpret_cast<const float4*>(xs + l * FDIM + 256);
        float4 v2 = *reinterpret_cast<const float4*>(xs + l * FDIM + 512);
        w0.x = fmaf(wl, v0.x, w0.x); w0.y = fmaf(wl, v0.y, w0.y);
        w0.z = fmaf(wl, v0.z, w0.z); w0.w = fmaf(wl, v0.w, w0.w);
        w1.x = fmaf(wl, v1.x, w1.x); w1.y = fmaf(wl, v1.y, w1.y);
        w1.z = fmaf(wl, v1.z, w1.z); w1.w = fmaf(wl, v1.w, w1.w);
        w2.x = fmaf(wl, v2.x, w2.x); w2.y = fmaf(wl, v2.y, w2.y);
        w2.z = fmaf(wl, v2.z, w2.z); w2.w = fmaf(wl, v2.w, w2.w);
      }
      sum0.x += w0.x; sum0.y += w0.y; sum0.z += w0.z; sum0.w += w0.w;
      sum1.x += w1.x; sum1.y += w1.y; sum1.z += w1.z; sum1.w += w1.w;
      sum2.x += w2.x; sum2.y += w2.y; sum2.z += w2.z; sum2.w += w2.w;
      sq0.x = fmaf(w0.x, w0.x, sq0.x); sq0.y = fmaf(w0.y, w0.y, sq0.y);
      sq0.z = fmaf(w0.z, w0.z, sq0.z); sq0.w = fmaf(w0.w, w0.w, sq0.w);
      sq1.x = fmaf(w1.x, w1.x, sq1.x); sq1.y = fmaf(w1.y, w1.y, sq1.y);
      sq1.z = fmaf(w1.z, w1.z, sq1.z); sq1.w = fmaf(w1.w, w1.w, sq1.w);
      sq2.x = fmaf(w2.x, w2.x, sq2.x); sq2.y = fmaf(w2.y, w2.y, sq2.y);
      sq2.z = fmaf(w2.z, w2.z, sq2.z); sq2.w = fmaf(w2.w, w2.w, sq2.w);
    }

    float* p = partial + (size_t)c * (2 * FDIM) + (size_t)lane * 4;
    *reinterpret_cast<float4*>(p)        = sum0;
    *reinterpret_cast<float4*>(p + 256)  = sum1;
    *reinterpret_cast<float4*>(p + 512)  = sum2;
    *reinterpret_cast<float4*>(p + FDIM)       = sq0;
    *reinterpret_cast<float4*>(p + FDIM + 256) = sq1;
    *reinterpret_cast<float4*>(p + FDIM + 512) = sq2;
  }
}

// ---------------- Kernel S: reduce chunk partials -> feats [B, 2F]
// grid = B * 12 (col-groups of 64), 256 thr = 64 cols x 4 chunk-slices, LDS reduce
__global__ __launch_bounds__(256) void kStats(
    const float* __restrict__ partial, const int* __restrict__ lengths,
    float* __restrict__ feats) {
  const int b  = blockIdx.x / 12;
  const int cg = blockIdx.x % 12;
  const int cl = threadIdx.x & 63;
  const int k  = threadIdx.x >> 6;      // 0..3
  const int f  = cg * 64 + cl;

  __shared__ int lenS[BNUM];
  __shared__ int cumS[BNUM + 1];
  if (threadIdx.x < BNUM) lenS[threadIdx.x] = lengths[threadIdx.x];
  __syncthreads();
  if (threadIdx.x == 0) {
    int acc = 0; cumS[0] = 0;
    #pragma unroll
    for (int bb = 0; bb < BNUM; ++bb) { acc += (lenS[bb] + 3) >> 2; cumS[bb + 1] = acc; }
  }
  __syncthreads();

  const int cBeg = cumS[b], cEnd = cumS[b + 1];
  float ms = 0.f, mq = 0.f;
  for (int cc = cBeg + k; cc < cEnd; cc += 4) {
    const float* p = partial + (size_t)cc * (2 * FDIM);
    ms += p[f];
    mq += p[FDIM + f];
  }
  __shared__ float rs[4][64], rq[4][64];
  rs[k][cl] = ms; rq[k][cl] = mq;
  __syncthreads();

  if (threadIdx.x < 64) {
    ms = rs[0][cl] + rs[1][cl] + rs[2][cl] + rs[3][cl];
    mq = rq[0][cl] + rq[1][cl] + rq[2][cl] + rq[3][cl];
    const int n = lenS[b];
    const float fn = (float)n;
    const float mean = ms / fmaxf(fn, 1.f);
    const float var = (mq - fn * mean * mean) / fmaxf(fn - 1.f, 1.f);
    const float sd = (n > 1) ? sqrtf(fmaxf(var, 0.f)) : 0.f;
    feats[(size_t)b * 2 * FDIM + f] = mean;
    feats[(size_t)b * 2 * FDIM + FDIM + f] = sd;
  }
}

// ---------------- Kernel C: h1 = relu(feats @ W1 + b1)
// grid = B * 4 (j-tiles of 128), 512 thr = 128 j-lanes x 4 k-slices
__global__ __launch_bounds__(512) void kFC1(
    const float* __restrict__ feats, const float* __restrict__ W1,
    const float* __restrict__ b1, float* __restrict__ h1) {
  const int b  = blockIdx.x >> 2;
  const int jt = blockIdx.x & 3;
  const int t  = threadIdx.x;
  const int jl = t & 127;
  const int kh = t >> 7;              // 0..3
  const int j  = jt * 128 + jl;

  __shared__ float fs[2 * FDIM];      // 6 KB
  __shared__ float red[4][128];       // 2 KB

  for (int i = t; i < 2 * FDIM; i += 512)
    fs[i] = feats[(size_t)b * 2 * FDIM + i];
  __syncthreads();

  const float* wcol = W1 + (size_t)kh * 384 * H1DIM + j;
  const float* fk = fs + kh * 384;
  float acc = 0.f;
  #pragma unroll 16
  for (int i = 0; i < 384; ++i)
    acc = fmaf(fk[i], wcol[(size_t)i * H1DIM], acc);
  red[kh][jl] = acc;
  __syncthreads();

  if (t < 128) {
    float a = red[0][t] + red[1][t] + red[2][t] + red[3][t] + b1[jt * 128 + t];
    h1[(size_t)b * H1DIM + jt * 128 + t] = fmaxf(a, 0.f);
  }
}

// ---------------- Kernel D: h2 = relu(h1 @ W2 + b2); out = h2 @ W3 + b3
// grid = B, 512 thr = 256 j-lanes x 2 k-halves
__global__ __launch_bounds__(512) void kFC23(
    const float* __restrict__ h1, const float* __restrict__ W2,
    const float* __restrict__ b2, const float* __restrict__ W3,
    const float* __restrict__ b3, float* __restrict__ out) {
  const int b = blockIdx.x;
  const int t = threadIdx.x;
  const int jl = t & 255;
  const int kh = t >> 8;              // 0..1

  __shared__ float hs[H1DIM];         // 2 KB
  __shared__ float red[2 * H2DIM];    // 2 KB
  __shared__ float wred[8];

  if (t < H1DIM) hs[t] = h1[(size_t)b * H1DIM + t];
  __syncthreads();

  const float* wcol = W2 + (size_t)kh * 256 * H2DIM + jl;
  const float* hk = hs + kh * 256;
  float acc = 0.f;
  #pragma unroll 16
  for (int i = 0; i < 256; ++i)
    acc = fmaf(hk[i], wcol[(size_t)i * H2DIM], acc);
  red[kh * H2DIM + jl] = acc;
  __syncthreads();

  float v = 0.f;
  if (t < H2DIM) {
    const float h2 = fmaxf(red[t] + red[H2DIM + t] + b2[t], 0.f);
    v = h2 * W3[t];
  }
  #pragma unroll
  for (int off = 32; off > 0; off >>= 1) v += __shfl_down(v, off, 64);
  if ((t & 63) == 0) wred[t >> 6] = v;
  __syncthreads();
  if (t == 0) {
    float r = b3[0];
    #pragma unroll
    for (int i = 0; i < 8; ++i) r += wred[i];
    out[b] = r;
  }
}

extern "C" void kernel_launch(void* const* d_in, const int* in_sizes, int n_in,
                              void* d_out, int out_size, void* d_ws, size_t ws_size,
                              hipStream_t stream) {
  const float* x       = (const float*)d_in[0];
  const int*   lengths = (const int*)  d_in[1];
  const float* lw      = (const float*)d_in[2];
  const float* W1      = (const float*)d_in[3];
  const float* b1      = (const float*)d_in[4];
  const float* W2      = (const float*)d_in[5];
  const float* b2      = (const float*)d_in[6];
  const float* W3      = (const float*)d_in[7];
  const float* b3      = (const float*)d_in[8];
  float* out = (float*)d_out;

  float* partial = (float*)d_ws;                              // MAXCH * 2F floats (25 MB)
  float* feats   = partial + (size_t)MAXCH * 2 * FDIM;        // B * 2F
  float* h1      = feats + (size_t)BNUM * 2 * FDIM;           // B * H1
  unsigned int* counter = (unsigned int*)(h1 + (size_t)BNUM * H1DIM);

  hipMemsetAsync(counter, 0, sizeof(unsigned int), stream);
  kA_partials<<<dim3(GA), dim3(192), 0, stream>>>(x, lengths, lw, partial, counter);
  kStats<<<dim3(BNUM * 12), dim3(256), 0, stream>>>(partial, lengths, feats);
  kFC1<<<dim3(BNUM * 4), dim3(512), 0, stream>>>(feats, W1, b1, h1);
  kFC23<<<dim3(BNUM), dim3(512), 0, stream>>>(h1, W2, b2, W3, b3, out);
}

// Round 7
// 89.272 us; speedup vs baseline: 1.9050x; 1.9050x over previous
//
#include <hip/hip_runtime.h>
#include <hip/hip_bf16.h>

#define LNUM 13
#define FDIM 768
#define SDIM 512
#define BNUM 32
#define H1DIM 512
#define H2DIM 256
#define GA0 992            // target blocks for apportionment
#define GPAD (GA0 + BNUM)  // 1024 launched blocks = 4 blocks/CU co-resident

// Shared deterministic apportionment: n_b = ceil(len_b * GA0 / T), BB = prefix(n_b).
// Computed identically (integer math) in kA and kStats.

// ---------------- Kernel A: block g handles a contiguous s-range of batch b
// (g in [BB[b], BB[b+1]) ), writes sum/sumsq partial slot g. Per-block steps
// <= ceil(T/GA0) = 9 vs mean 8.24 -> worst-CU skew ~1.09. No atomics.
__global__ __launch_bounds__(192) void kA_partials(
    const float* __restrict__ x, const int* __restrict__ lengths,
    const float* __restrict__ lw, float* __restrict__ partial) {
  __shared__ int lenS[BNUM];
  __shared__ int BB[BNUM + 1];
  __shared__ float wS[LNUM];
  const int tid = threadIdx.x;

  if (tid < BNUM) lenS[tid] = lengths[tid];
  __syncthreads();
  if (tid == 0) {
    int T = 0;
    #pragma unroll
    for (int b = 0; b < BNUM; ++b) T += lenS[b];
    int acc = 0; BB[0] = 0;
    #pragma unroll
    for (int b = 0; b < BNUM; ++b) {
      int nb = (T > 0 && lenS[b] > 0) ? (lenS[b] * GA0 + T - 1) / T : 0;
      acc += nb; BB[b + 1] = acc;
    }
    float m = lw[0];
    #pragma unroll
    for (int l = 1; l < LNUM; ++l) m = fmaxf(m, lw[l]);
    float e[LNUM]; float s = 0.f;
    #pragma unroll
    for (int l = 0; l < LNUM; ++l) { e[l] = expf(lw[l] - m); s += e[l]; }
    #pragma unroll
    for (int l = 0; l < LNUM; ++l) wS[l] = e[l] / s;
  }
  __syncthreads();

  const int g = blockIdx.x;
  if (g >= BB[BNUM]) return;           // idle block; its slot is never read

  // largest b with BB[b] <= g (empty ranges are skipped by construction)
  int lo = 0, hi = BNUM;
  while (hi - lo > 1) { int mid = (lo + hi) >> 1; if (g >= BB[mid]) lo = mid; else hi = mid; }
  const int b   = lo;
  const int i   = g - BB[b];
  const int n   = BB[b + 1] - BB[b];
  const int len = lenS[b];
  const int base = len / n, rem = len % n;
  const int s0 = i * base + min(i, rem);
  const int cnt = base + (i < rem ? 1 : 0);

  float4 sum = make_float4(0.f, 0.f, 0.f, 0.f);
  float4 sq  = make_float4(0.f, 0.f, 0.f, 0.f);
  const float* xb = x + (size_t)b * SDIM * (LNUM * FDIM) + (size_t)tid * 4;

  for (int s = s0; s < s0 + cnt; ++s) {
    const float* xs = xb + (size_t)s * (LNUM * FDIM);
    float4 word = make_float4(0.f, 0.f, 0.f, 0.f);
    #pragma unroll
    for (int l = 0; l < LNUM; ++l) {
      float4 v = *reinterpret_cast<const float4*>(xs + l * FDIM);
      const float wl = wS[l];
      word.x = fmaf(wl, v.x, word.x);
      word.y = fmaf(wl, v.y, word.y);
      word.z = fmaf(wl, v.z, word.z);
      word.w = fmaf(wl, v.w, word.w);
    }
    sum.x += word.x; sum.y += word.y; sum.z += word.z; sum.w += word.w;
    sq.x = fmaf(word.x, word.x, sq.x);
    sq.y = fmaf(word.y, word.y, sq.y);
    sq.z = fmaf(word.z, word.z, sq.z);
    sq.w = fmaf(word.w, word.w, sq.w);
  }

  float* p = partial + (size_t)g * (2 * FDIM) + (size_t)tid * 4;
  *reinterpret_cast<float4*>(p) = sum;        // zeros if cnt==0 (slot is read)
  *reinterpret_cast<float4*>(p + FDIM) = sq;
}

// ---------------- Kernel S: reduce slots [BB[b], BB[b+1]) -> feats [B, 2F]
// grid = B * 12 (col-groups of 64), 256 thr = 64 cols x 4 slot-slices, LDS reduce
__global__ __launch_bounds__(256) void kStats(
    const float* __restrict__ partial, const int* __restrict__ lengths,
    float* __restrict__ feats) {
  const int b  = blockIdx.x / 12;
  const int cg = blockIdx.x % 12;
  const int cl = threadIdx.x & 63;
  const int k  = threadIdx.x >> 6;      // 0..3
  const int f  = cg * 64 + cl;

  __shared__ int lenS[BNUM];
  __shared__ int BB[BNUM + 1];
  if (threadIdx.x < BNUM) lenS[threadIdx.x] = lengths[threadIdx.x];
  __syncthreads();
  if (threadIdx.x == 0) {
    int T = 0;
    #pragma unroll
    for (int bb = 0; bb < BNUM; ++bb) T += lenS[bb];
    int acc = 0; BB[0] = 0;
    #pragma unroll
    for (int bb = 0; bb < BNUM; ++bb) {
      int nb = (T > 0 && lenS[bb] > 0) ? (lenS[bb] * GA0 + T - 1) / T : 0;
      acc += nb; BB[bb + 1] = acc;
    }
  }
  __syncthreads();

  const int cBeg = BB[b], cEnd = BB[b + 1];
  float ms = 0.f, mq = 0.f;
  for (int cc = cBeg + k; cc < cEnd; cc += 4) {
    const float* p = partial + (size_t)cc * (2 * FDIM);
    ms += p[f];
    mq += p[FDIM + f];
  }
  __shared__ float rs[4][64], rq[4][64];
  rs[k][cl] = ms; rq[k][cl] = mq;
  __syncthreads();

  if (threadIdx.x < 64) {
    ms = rs[0][cl] + rs[1][cl] + rs[2][cl] + rs[3][cl];
    mq = rq[0][cl] + rq[1][cl] + rq[2][cl] + rq[3][cl];
    const int n = lenS[b];
    const float fn = (float)n;
    const float mean = ms / fmaxf(fn, 1.f);
    const float var = (mq - fn * mean * mean) / fmaxf(fn - 1.f, 1.f);
    const float sd = (n > 1) ? sqrtf(fmaxf(var, 0.f)) : 0.f;
    feats[(size_t)b * 2 * FDIM + f] = mean;
    feats[(size_t)b * 2 * FDIM + FDIM + f] = sd;
  }
}

// ---------------- Kernel C: h1 = relu(feats @ W1 + b1)
// grid = B * 4 (j-tiles of 128), 512 thr = 128 j-lanes x 4 k-slices
__global__ __launch_bounds__(512) void kFC1(
    const float* __restrict__ feats, const float* __restrict__ W1,
    const float* __restrict__ b1, float* __restrict__ h1) {
  const int b  = blockIdx.x >> 2;
  const int jt = blockIdx.x & 3;
  const int t  = threadIdx.x;
  const int jl = t & 127;
  const int kh = t >> 7;              // 0..3
  const int j  = jt * 128 + jl;

  __shared__ float fs[2 * FDIM];      // 6 KB
  __shared__ float red[4][128];       // 2 KB

  for (int i = t; i < 2 * FDIM; i += 512)
    fs[i] = feats[(size_t)b * 2 * FDIM + i];
  __syncthreads();

  const float* wcol = W1 + (size_t)kh * 384 * H1DIM + j;
  const float* fk = fs + kh * 384;
  float acc = 0.f;
  #pragma unroll 16
  for (int i = 0; i < 384; ++i)
    acc = fmaf(fk[i], wcol[(size_t)i * H1DIM], acc);
  red[kh][jl] = acc;
  __syncthreads();

  if (t < 128) {
    float a = red[0][t] + red[1][t] + red[2][t] + red[3][t] + b1[jt * 128 + t];
    h1[(size_t)b * H1DIM + jt * 128 + t] = fmaxf(a, 0.f);
  }
}

// ---------------- Kernel D: h2 = relu(h1 @ W2 + b2); out = h2 @ W3 + b3
// grid = B, 512 thr = 256 j-lanes x 2 k-halves
__global__ __launch_bounds__(512) void kFC23(
    const float* __restrict__ h1, const float* __restrict__ W2,
    const float* __restrict__ b2, const float* __restrict__ W3,
    const float* __restrict__ b3, float* __restrict__ out) {
  const int b = blockIdx.x;
  const int t = threadIdx.x;
  const int jl = t & 255;
  const int kh = t >> 8;              // 0..1

  __shared__ float hs[H1DIM];         // 2 KB
  __shared__ float red[2 * H2DIM];    // 2 KB
  __shared__ float wred[8];

  if (t < H1DIM) hs[t] = h1[(size_t)b * H1DIM + t];
  __syncthreads();

  const float* wcol = W2 + (size_t)kh * 256 * H2DIM + jl;
  const float* hk = hs + kh * 256;
  float acc = 0.f;
  #pragma unroll 16
  for (int i = 0; i < 256; ++i)
    acc = fmaf(hk[i], wcol[(size_t)i * H2DIM], acc);
  red[kh * H2DIM + jl] = acc;
  __syncthreads();

  float v = 0.f;
  if (t < H2DIM) {
    const float h2 = fmaxf(red[t] + red[H2DIM + t] + b2[t], 0.f);
    v = h2 * W3[t];
  }
  #pragma unroll
  for (int off = 32; off > 0; off >>= 1) v += __shfl_down(v, off, 64);
  if ((t & 63) == 0) wred[t >> 6] = v;
  __syncthreads();
  if (t == 0) {
    float r = b3[0];
    #pragma unroll
    for (int i = 0; i < 8; ++i) r += wred[i];
    out[b] = r;
  }
}

extern "C" void kernel_launch(void* const* d_in, const int* in_sizes, int n_in,
                              void* d_out, int out_size, void* d_ws, size_t ws_size,
                              hipStream_t stream) {
  const float* x       = (const float*)d_in[0];
  const int*   lengths = (const int*)  d_in[1];
  const float* lw      = (const float*)d_in[2];
  const float* W1      = (const float*)d_in[3];
  const float* b1      = (const float*)d_in[4];
  const float* W2      = (const float*)d_in[5];
  const float* b2      = (const float*)d_in[6];
  const float* W3      = (const float*)d_in[7];
  const float* b3      = (const float*)d_in[8];
  float* out = (float*)d_out;

  float* partial = (float*)d_ws;                              // GPAD * 2F floats (6.3 MB)
  float* feats   = partial + (size_t)GPAD * 2 * FDIM;         // B * 2F
  float* h1      = feats + (size_t)BNUM * 2 * FDIM;           // B * H1

  kA_partials<<<dim3(GPAD), dim3(192), 0, stream>>>(x, lengths, lw, partial);
  kStats<<<dim3(BNUM * 12), dim3(256), 0, stream>>>(partial, lengths, feats);
  kFC1<<<dim3(BNUM * 4), dim3(512), 0, stream>>>(feats, W1, b1, h1);
  kFC23<<<dim3(BNUM), dim3(512), 0, stream>>>(h1, W2, b2, W3, b3, out);
}